// Round 1
// baseline (2630.958 us; speedup 1.0000x reference)
//
#include <hip/hip_runtime.h>

// ---------- types & helpers ----------
using bf16x8 = __attribute__((ext_vector_type(8))) __bf16;
using f32x4  = __attribute__((ext_vector_type(4))) float;

#define AS1(p) ((const __attribute__((address_space(1))) void*)(p))
#define AS3(p) ((__attribute__((address_space(3))) void*)(p))

__device__ __forceinline__ unsigned short f2bf(float f) {
  unsigned u = __float_as_uint(f);
  u += 0x7fffu + ((u >> 16) & 1u);          // RNE
  return (unsigned short)(u >> 16);
}
__device__ __forceinline__ float bf2f(unsigned short h) {
  return __uint_as_float(((unsigned)h) << 16);
}

// ---------- K0: weight conversion (transposed to [N][K] bf16) ----------
__global__ __launch_bounds__(256) void convert_weights(
    const float* __restrict__ wq, const float* __restrict__ wo,
    const float* __restrict__ w1, const float* __restrict__ w2,
    const float* __restrict__ kv,
    unsigned short* __restrict__ wqT, unsigned short* __restrict__ woT,
    unsigned short* __restrict__ w1T, unsigned short* __restrict__ w2T,
    unsigned short* __restrict__ kvb, unsigned short* __restrict__ kvT) {
  int idx = blockIdx.x * 256 + threadIdx.x;       // 0 .. 1048575, coalesced WRITE index
  int n = idx >> 10, k = idx & 1023;
  int src = k * 1024 + n;                         // strided read (L2-amortized)
  wqT[idx] = f2bf(wq[src]);
  woT[idx] = f2bf(wo[src]);
  w1T[idx] = f2bf(w1[src]);
  w2T[idx] = f2bf(w2[src]);
  if (idx < 65536) {
    kvb[idx] = f2bf(kv[idx]);                     // [r][d], coalesced both ways
    int h = idx >> 12, d = (idx >> 6) & 63, r = idx & 63;
    kvT[idx] = f2bf(kv[r * 1024 + h * 64 + d]);   // [h][d][r]
  }
}

// ---------- GEMM: C[M,1024] = A[M,1024] @ B (B given transposed [n][k] bf16) ----------
// EPI 0: store bf16 * scale     EPI 1: gelu(acc + bias) store bf16
// EPI 2: acc + bias + resid, column-sum per 128-row tile -> atomicAdd(pool)/4096
template <int EPI, bool AF32>
__global__ __launch_bounds__(256) void gemm128(
    const void* __restrict__ Ap, const unsigned short* __restrict__ BT,
    unsigned short* __restrict__ C, const float* __restrict__ bias,
    const unsigned short* __restrict__ resid, float* __restrict__ pool,
    float scale) {
  __shared__ unsigned short As[128 * 32];
  __shared__ unsigned short Bs[128 * 32];
  const int tid = threadIdx.x;
  const int lane = tid & 63, wave = tid >> 6;
  const int wr = wave >> 1, wc = wave & 1;
  const int l15 = lane & 15, l4 = lane >> 4;
  const int row0 = blockIdx.y * 128, col0 = blockIdx.x * 128;

  f32x4 acc[4][4];
#pragma unroll
  for (int i = 0; i < 4; i++)
#pragma unroll
    for (int j = 0; j < 4; j++) acc[i][j] = f32x4{0.f, 0.f, 0.f, 0.f};

  for (int k0 = 0; k0 < 1024; k0 += 32) {
    if (AF32) {
      const float* A = (const float*)Ap;
#pragma unroll
      for (int s = 0; s < 4; s++) {
        int c = tid + 256 * s;                 // 1024 chunks of 4 floats
        int r = c >> 3, c4 = c & 7;
        const float4 v = *(const float4*)(A + (size_t)(row0 + r) * 1024 + k0 + c4 * 4);
        ushort4 b;
        b.x = f2bf(v.x); b.y = f2bf(v.y); b.z = f2bf(v.z); b.w = f2bf(v.w);
        *(ushort4*)(As + c * 4) = b;
      }
    } else {
      const unsigned short* A = (const unsigned short*)Ap;
#pragma unroll
      for (int t = 0; t < 2; t++) {
        int c = wave * 128 + t * 64 + lane;    // 512 chunks of 16B
        int r = c >> 2, c8 = c & 3;
        __builtin_amdgcn_global_load_lds(AS1(A + (size_t)(row0 + r) * 1024 + k0 + c8 * 8),
                                         AS3(As + (wave * 128 + t * 64) * 8), 16, 0, 0);
      }
    }
#pragma unroll
    for (int t = 0; t < 2; t++) {
      int c = wave * 128 + t * 64 + lane;
      int r = c >> 2, c8 = c & 3;
      __builtin_amdgcn_global_load_lds(AS1(BT + (size_t)(col0 + r) * 1024 + k0 + c8 * 8),
                                       AS3(Bs + (wave * 128 + t * 64) * 8), 16, 0, 0);
    }
    __syncthreads();

    bf16x8 af[4], bfr[4];
#pragma unroll
    for (int i = 0; i < 4; i++)
      af[i] = *(const bf16x8*)(As + (wr * 64 + i * 16 + l15) * 32 + l4 * 8);
#pragma unroll
    for (int j = 0; j < 4; j++)
      bfr[j] = *(const bf16x8*)(Bs + (wc * 64 + j * 16 + l15) * 32 + l4 * 8);
#pragma unroll
    for (int i = 0; i < 4; i++)
#pragma unroll
      for (int j = 0; j < 4; j++)
        acc[i][j] = __builtin_amdgcn_mfma_f32_16x16x32_bf16(af[i], bfr[j], acc[i][j], 0, 0, 0);
    __syncthreads();
  }

  if (EPI == 0) {
#pragma unroll
    for (int i = 0; i < 4; i++)
#pragma unroll
      for (int j = 0; j < 4; j++)
#pragma unroll
        for (int v = 0; v < 4; v++) {
          int row = row0 + wr * 64 + i * 16 + l4 * 4 + v;
          int col = col0 + wc * 64 + j * 16 + l15;
          C[(size_t)row * 1024 + col] = f2bf(acc[i][j][v] * scale);
        }
  } else if (EPI == 1) {
#pragma unroll
    for (int j = 0; j < 4; j++) {
      int col = col0 + wc * 64 + j * 16 + l15;
      float bj = bias[col];
#pragma unroll
      for (int i = 0; i < 4; i++)
#pragma unroll
        for (int v = 0; v < 4; v++) {
          int row = row0 + wr * 64 + i * 16 + l4 * 4 + v;
          float val = acc[i][j][v] + bj;
          float g = 0.5f * val * (1.0f + erff(val * 0.70710678118654752f));
          C[(size_t)row * 1024 + col] = f2bf(g);
        }
    }
  } else {  // EPI == 2: residual + bias + mean-pool
    float cs[4] = {0.f, 0.f, 0.f, 0.f};
#pragma unroll
    for (int j = 0; j < 4; j++) {
      int col = col0 + wc * 64 + j * 16 + l15;
      float bj = bias[col];
#pragma unroll
      for (int i = 0; i < 4; i++)
#pragma unroll
        for (int v = 0; v < 4; v++) {
          int row = row0 + wr * 64 + i * 16 + l4 * 4 + v;
          float val = acc[i][j][v] + bj + bf2f(resid[(size_t)row * 1024 + col]);
          cs[j] += val;
        }
    }
#pragma unroll
    for (int j = 0; j < 4; j++) {
      cs[j] += __shfl_xor(cs[j], 16);
      cs[j] += __shfl_xor(cs[j], 32);
    }
    if (l4 == 0) {
      int b = row0 >> 12;  // 4096 tokens per batch, tiles never straddle
#pragma unroll
      for (int j = 0; j < 4; j++) {
        int col = col0 + wc * 64 + j * 16 + l15;
        atomicAdd(pool + b * 1024 + col, cs[j] * (1.0f / 4096.0f));
      }
    }
  }
}

// ---------- K2: latent attention (128 tokens x 2 heads per block) ----------
__global__ __launch_bounds__(256) void attn_kernel(
    const unsigned short* __restrict__ q, const unsigned short* __restrict__ kvb,
    const unsigned short* __restrict__ kvT, unsigned short* __restrict__ outp) {
  __shared__ unsigned short smem[32768];  // 64 KB
  unsigned short* qs   = smem;            // [128][128]  (aliased by attn later)
  unsigned short* kvs  = smem + 16384;    // [2][64 r][64 d]
  unsigned short* kvTs = smem + 24576;    // [2][64 d][64 r]
  const int tid = threadIdx.x;
  const int lane = tid & 63, wave = tid >> 6;
  const int wr = wave >> 1, wc = wave & 1;
  const int l15 = lane & 15, l4 = lane >> 4;
  const int hp = blockIdx.x, row0 = blockIdx.y * 128;

#pragma unroll
  for (int t = 0; t < 8; t++) {           // q tile: 2048 x 16B
    int c = wave * 512 + t * 64 + lane;
    int r = c >> 4, c8 = c & 15;
    __builtin_amdgcn_global_load_lds(AS1(q + (size_t)(row0 + r) * 1024 + hp * 128 + c8 * 8),
                                     AS3(qs + (wave * 512 + t * 64) * 8), 16, 0, 0);
  }
#pragma unroll
  for (int t = 0; t < 4; t++) {           // kv + kvT: 1024 x 16B each
    int c = wave * 256 + t * 64 + lane;
    int h = c >> 9, r = (c >> 3) & 63, c8 = c & 7;
    __builtin_amdgcn_global_load_lds(AS1(kvb + r * 1024 + (hp * 2 + h) * 64 + c8 * 8),
                                     AS3(kvs + (wave * 256 + t * 64) * 8), 16, 0, 0);
    __builtin_amdgcn_global_load_lds(AS1(kvT + (hp * 2 + h) * 4096 + (c & 511) * 8),
                                     AS3(kvTs + (wave * 256 + t * 64) * 8), 16, 0, 0);
  }
  __syncthreads();

  // scores[row][r] for head wc, rows wr*64..+63
  f32x4 sc[4][4];
#pragma unroll
  for (int i = 0; i < 4; i++)
#pragma unroll
    for (int j = 0; j < 4; j++) sc[i][j] = f32x4{0.f, 0.f, 0.f, 0.f};
#pragma unroll
  for (int ks = 0; ks < 2; ks++) {
    bf16x8 af[4], bfr[4];
#pragma unroll
    for (int i = 0; i < 4; i++)
      af[i] = *(const bf16x8*)(qs + (wr * 64 + i * 16 + l15) * 128 + wc * 64 + ks * 32 + l4 * 8);
#pragma unroll
    for (int j = 0; j < 4; j++)
      bfr[j] = *(const bf16x8*)(kvs + wc * 4096 + (j * 16 + l15) * 64 + ks * 32 + l4 * 8);
#pragma unroll
    for (int i = 0; i < 4; i++)
#pragma unroll
      for (int j = 0; j < 4; j++)
        sc[i][j] = __builtin_amdgcn_mfma_f32_16x16x32_bf16(af[i], bfr[j], sc[i][j], 0, 0, 0);
  }
  __syncthreads();  // all qs reads done; attn aliases qs

  unsigned short* attn = qs;  // [2][128][64], wave-private regions
#pragma unroll
  for (int i = 0; i < 4; i++)
#pragma unroll
    for (int v = 0; v < 4; v++) {
      float m = fmaxf(fmaxf(sc[i][0][v], sc[i][1][v]), fmaxf(sc[i][2][v], sc[i][3][v]));
#pragma unroll
      for (int msk = 1; msk <= 8; msk <<= 1) m = fmaxf(m, __shfl_xor(m, msk));
      float e0 = __expf(sc[i][0][v] - m), e1 = __expf(sc[i][1][v] - m);
      float e2 = __expf(sc[i][2][v] - m), e3 = __expf(sc[i][3][v] - m);
      float s = e0 + e1 + e2 + e3;
#pragma unroll
      for (int msk = 1; msk <= 8; msk <<= 1) s += __shfl_xor(s, msk);
      float inv = 1.0f / s;
      int row = wr * 64 + i * 16 + l4 * 4 + v;
      attn[wc * 8192 + row * 64 + 0 * 16 + l15] = f2bf(e0 * inv);
      attn[wc * 8192 + row * 64 + 1 * 16 + l15] = f2bf(e1 * inv);
      attn[wc * 8192 + row * 64 + 2 * 16 + l15] = f2bf(e2 * inv);
      attn[wc * 8192 + row * 64 + 3 * 16 + l15] = f2bf(e3 * inv);
    }

  // out[row][d] = attn @ kv   (B = kvT[d][r])
  f32x4 o[4][4];
#pragma unroll
  for (int i = 0; i < 4; i++)
#pragma unroll
    for (int j = 0; j < 4; j++) o[i][j] = f32x4{0.f, 0.f, 0.f, 0.f};
#pragma unroll
  for (int ks = 0; ks < 2; ks++) {
    bf16x8 af[4], bfr[4];
#pragma unroll
    for (int i = 0; i < 4; i++)
      af[i] = *(const bf16x8*)(attn + wc * 8192 + (wr * 64 + i * 16 + l15) * 64 + ks * 32 + l4 * 8);
#pragma unroll
    for (int j = 0; j < 4; j++)
      bfr[j] = *(const bf16x8*)(kvTs + wc * 4096 + (j * 16 + l15) * 64 + ks * 32 + l4 * 8);
#pragma unroll
    for (int i = 0; i < 4; i++)
#pragma unroll
      for (int j = 0; j < 4; j++)
        o[i][j] = __builtin_amdgcn_mfma_f32_16x16x32_bf16(af[i], bfr[j], o[i][j], 0, 0, 0);
  }
#pragma unroll
  for (int i = 0; i < 4; i++)
#pragma unroll
    for (int j = 0; j < 4; j++)
#pragma unroll
      for (int v = 0; v < 4; v++) {
        int row = row0 + wr * 64 + i * 16 + l4 * 4 + v;
        int col = (hp * 2 + wc) * 64 + j * 16 + l15;
        outp[(size_t)row * 1024 + col] = f2bf(o[i][j][v]);
      }
}

// ---------- launch ----------
extern "C" void kernel_launch(void* const* d_in, const int* in_sizes, int n_in,
                              void* d_out, int out_size, void* d_ws, size_t ws_size,
                              hipStream_t stream) {
  const float* x  = (const float*)d_in[0];
  const float* wq = (const float*)d_in[1];
  const float* kv = (const float*)d_in[2];
  const float* wo = (const float*)d_in[3];
  const float* w1 = (const float*)d_in[4];
  const float* b1 = (const float*)d_in[5];
  const float* w2 = (const float*)d_in[6];
  const float* b2 = (const float*)d_in[7];
  char* ws = (char*)d_ws;
  const size_t MB = 1024 * 1024;
  unsigned short* wqT = (unsigned short*)(ws + 0 * MB);
  unsigned short* woT = (unsigned short*)(ws + 2 * MB);
  unsigned short* w1T = (unsigned short*)(ws + 4 * MB);
  unsigned short* w2T = (unsigned short*)(ws + 6 * MB);
  unsigned short* kvb = (unsigned short*)(ws + 8 * MB);
  unsigned short* kvT = (unsigned short*)(ws + 8 * MB + 256 * 1024);
  unsigned short* buf1 = (unsigned short*)(ws + 16 * MB);             // q, then y
  unsigned short* buf2 = (unsigned short*)(ws + 16 * MB + 256 * MB);  // attn_out, then h
  float* out = (float*)d_out;

  hipMemsetAsync(d_out, 0, (size_t)out_size * sizeof(float), stream);
  convert_weights<<<4096, 256, 0, stream>>>(wq, wo, w1, w2, kv, wqT, woT, w1T, w2T, kvb, kvT);

  dim3 g(8, 1024);  // x = col tile (8), y = row tile (1024)
  // K1: q = (x @ wq) * R^-0.5
  gemm128<0, true ><<<g, 256, 0, stream>>>(x, wqT, buf1, nullptr, nullptr, nullptr, 0.125f);
  // K2: latent attention
  attn_kernel<<<g, 256, 0, stream>>>(buf1, kvb, kvT, buf2);
  // K3: y = attn_out @ wo
  gemm128<0, false><<<g, 256, 0, stream>>>(buf2, woT, buf1, nullptr, nullptr, nullptr, 1.0f);
  // K4: h = gelu(y @ w1 + b1)
  gemm128<1, false><<<g, 256, 0, stream>>>(buf1, w1T, buf2, b1, nullptr, nullptr, 1.0f);
  // K5: out_final = h @ w2 + b2 + y  -> mean-pool into d_out
  gemm128<2, false><<<g, 256, 0, stream>>>(buf2, w2T, nullptr, b2, buf1, out, 1.0f);
}

// Round 2
// 2441.637 us; speedup vs baseline: 1.0775x; 1.0775x over previous
//
#include <hip/hip_runtime.h>

// ---------- types & helpers ----------
using bf16x8 = __attribute__((ext_vector_type(8))) __bf16;
using f32x4  = __attribute__((ext_vector_type(4))) float;

#define AS1(p) ((const __attribute__((address_space(1))) void*)(p))
#define AS3(p) ((__attribute__((address_space(3))) void*)(p))

__device__ __forceinline__ unsigned short f2bf(float f) {
  unsigned u = __float_as_uint(f);
  u += 0x7fffu + ((u >> 16) & 1u);          // RNE
  return (unsigned short)(u >> 16);
}
__device__ __forceinline__ float bf2f(unsigned short h) {
  return __uint_as_float(((unsigned)h) << 16);
}

// ---------- K0a: coalesced weight transpose fp32[k][n] -> bf16[n][k] ----------
__global__ __launch_bounds__(256) void transpose_w(
    const float* __restrict__ wq, const float* __restrict__ wo,
    const float* __restrict__ w1, const float* __restrict__ w2,
    unsigned short* __restrict__ wqT, unsigned short* __restrict__ woT,
    unsigned short* __restrict__ w1T, unsigned short* __restrict__ w2T) {
  __shared__ float tile[64][65];
  const int z = blockIdx.z;
  const float* src = z == 0 ? wq : z == 1 ? wo : z == 2 ? w1 : w2;
  unsigned short* dst = z == 0 ? wqT : z == 1 ? woT : z == 2 ? w1T : w2T;
  const int tx = threadIdx.x & 63, ty = threadIdx.x >> 6;
  const int n0 = blockIdx.x * 64, k0 = blockIdx.y * 64;
#pragma unroll
  for (int i = 0; i < 16; i++) {
    int k = ty * 16 + i;
    tile[k][tx] = src[(size_t)(k0 + k) * 1024 + n0 + tx];   // coalesced read
  }
  __syncthreads();
#pragma unroll
  for (int i = 0; i < 16; i++) {
    int n = ty * 16 + i;
    dst[(size_t)(n0 + n) * 1024 + k0 + tx] = f2bf(tile[tx][n]);  // coalesced write
  }
}

// ---------- K0b: kv conversion (tiny) ----------
__global__ __launch_bounds__(256) void convert_kv(
    const float* __restrict__ kv, unsigned short* __restrict__ kvb,
    unsigned short* __restrict__ kvT) {
  int idx = blockIdx.x * 256 + threadIdx.x;       // 0..65535
  kvb[idx] = f2bf(kv[idx]);                       // [r][d]
  int h = idx >> 12, d = (idx >> 6) & 63, r = idx & 63;
  kvT[idx] = f2bf(kv[r * 1024 + h * 64 + d]);     // [h][d][r]
}

// ---------- GEMM: C[M,1024] = A[M,1024] @ B (B given transposed [n][k] bf16) ----------
// LDS layout: 16B slot p = r*4 + (c ^ ((r>>1)&3)) holds row r, k-chunk c (bank-conflict-free)
// EPI 0: store bf16 * scale     EPI 1: gelu(acc + bias) store bf16
// EPI 2: acc + bias + resid, column-sum per 128-row tile -> atomicAdd(pool)/4096
template <int EPI, bool AF32>
__global__ __launch_bounds__(256) void gemm128(
    const void* __restrict__ Ap, const unsigned short* __restrict__ BT,
    unsigned short* __restrict__ C, const float* __restrict__ bias,
    const unsigned short* __restrict__ resid, float* __restrict__ pool,
    float scale) {
  __shared__ unsigned short As[128 * 32];
  __shared__ unsigned short Bs[128 * 32];
  const int tid = threadIdx.x;
  const int lane = tid & 63, wave = tid >> 6;
  const int wr = wave >> 1, wc = wave & 1;
  const int l15 = lane & 15, l4 = lane >> 4;
  // XCD-grouping swizzle: the 8 col-tiles sharing a row-panel get identical bid%8
  // (same XCD under round-robin dispatch) and sit within 64 dispatch slots.
  const int bid = blockIdx.y * 8 + blockIdx.x;
  const int xcd = bid & 7, j = bid >> 3;
  const int row0 = ((xcd << 7) | (j >> 3)) * 128;
  const int col0 = (j & 7) * 128;
  const int swz = (l15 >> 1) & 3;                 // frag-read chunk swizzle

  f32x4 acc[4][4];
#pragma unroll
  for (int i = 0; i < 4; i++)
#pragma unroll
    for (int jj = 0; jj < 4; jj++) acc[i][jj] = f32x4{0.f, 0.f, 0.f, 0.f};

  for (int k0 = 0; k0 < 1024; k0 += 32) {
    if (AF32) {
      const float* A = (const float*)Ap;
#pragma unroll
      for (int s = 0; s < 4; s++) {
        int c = tid + 256 * s;                 // 1024 chunks of 4 floats (8B bf16)
        int r = c >> 3, c4 = c & 7;
        const float4 v = *(const float4*)(A + (size_t)(row0 + r) * 1024 + k0 + c4 * 4);
        ushort4 b;
        b.x = f2bf(v.x); b.y = f2bf(v.y); b.z = f2bf(v.z); b.w = f2bf(v.w);
        int cc = (c4 >> 1) ^ ((r >> 1) & 3), h = c4 & 1;
        *(ushort4*)(As + r * 32 + cc * 8 + h * 4) = b;
      }
    } else {
      const unsigned short* A = (const unsigned short*)Ap;
#pragma unroll
      for (int t = 0; t < 2; t++) {
        int p = wave * 128 + t * 64 + lane;    // LDS 16B slot
        int r = p >> 2, c = (p & 3) ^ ((r >> 1) & 3);
        __builtin_amdgcn_global_load_lds(AS1(A + (size_t)(row0 + r) * 1024 + k0 + c * 8),
                                         AS3(As + p * 8), 16, 0, 0);
      }
    }
#pragma unroll
    for (int t = 0; t < 2; t++) {
      int p = wave * 128 + t * 64 + lane;
      int r = p >> 2, c = (p & 3) ^ ((r >> 1) & 3);
      __builtin_amdgcn_global_load_lds(AS1(BT + (size_t)(col0 + r) * 1024 + k0 + c * 8),
                                       AS3(Bs + p * 8), 16, 0, 0);
    }
    __syncthreads();

    bf16x8 af[4], bfr[4];
#pragma unroll
    for (int i = 0; i < 4; i++)
      af[i] = *(const bf16x8*)(As + (wr * 64 + i * 16 + l15) * 32 + (l4 ^ swz) * 8);
#pragma unroll
    for (int jj = 0; jj < 4; jj++)
      bfr[jj] = *(const bf16x8*)(Bs + (wc * 64 + jj * 16 + l15) * 32 + (l4 ^ swz) * 8);
#pragma unroll
    for (int i = 0; i < 4; i++)
#pragma unroll
      for (int jj = 0; jj < 4; jj++)
        acc[i][jj] = __builtin_amdgcn_mfma_f32_16x16x32_bf16(af[i], bfr[jj], acc[i][jj], 0, 0, 0);
    __syncthreads();
  }

  if (EPI == 0) {
#pragma unroll
    for (int i = 0; i < 4; i++)
#pragma unroll
      for (int jj = 0; jj < 4; jj++)
#pragma unroll
        for (int v = 0; v < 4; v++) {
          int row = row0 + wr * 64 + i * 16 + l4 * 4 + v;
          int col = col0 + wc * 64 + jj * 16 + l15;
          C[(size_t)row * 1024 + col] = f2bf(acc[i][jj][v] * scale);
        }
  } else if (EPI == 1) {
#pragma unroll
    for (int jj = 0; jj < 4; jj++) {
      int col = col0 + wc * 64 + jj * 16 + l15;
      float bj = bias[col];
#pragma unroll
      for (int i = 0; i < 4; i++)
#pragma unroll
        for (int v = 0; v < 4; v++) {
          int row = row0 + wr * 64 + i * 16 + l4 * 4 + v;
          float val = acc[i][jj][v] + bj;
          float g = 0.5f * val * (1.0f + erff(val * 0.70710678118654752f));
          C[(size_t)row * 1024 + col] = f2bf(g);
        }
    }
  } else {  // EPI == 2: residual + bias + mean-pool
    float cs[4] = {0.f, 0.f, 0.f, 0.f};
#pragma unroll
    for (int jj = 0; jj < 4; jj++) {
      int col = col0 + wc * 64 + jj * 16 + l15;
      float bj = bias[col];
#pragma unroll
      for (int i = 0; i < 4; i++)
#pragma unroll
        for (int v = 0; v < 4; v++) {
          int row = row0 + wr * 64 + i * 16 + l4 * 4 + v;
          float val = acc[i][jj][v] + bj + bf2f(resid[(size_t)row * 1024 + col]);
          cs[jj] += val;
        }
    }
#pragma unroll
    for (int jj = 0; jj < 4; jj++) {
      cs[jj] += __shfl_xor(cs[jj], 16);
      cs[jj] += __shfl_xor(cs[jj], 32);
    }
    if (l4 == 0) {
      int b = row0 >> 12;  // 4096 tokens per batch, tiles never straddle
#pragma unroll
      for (int jj = 0; jj < 4; jj++) {
        int col = col0 + wc * 64 + jj * 16 + l15;
        atomicAdd(pool + b * 1024 + col, cs[jj] * (1.0f / 4096.0f));
      }
    }
  }
}

// ---------- K2: latent attention (128 tokens x 2 heads per block) ----------
__global__ __launch_bounds__(256) void attn_kernel(
    const unsigned short* __restrict__ q, const unsigned short* __restrict__ kvb,
    const unsigned short* __restrict__ kvT, unsigned short* __restrict__ outp) {
  __shared__ unsigned short smem[32768];  // 64 KB
  unsigned short* qs   = smem;            // [128][128]  (aliased by attn later)
  unsigned short* kvs  = smem + 16384;    // [2][64 r][64 d]
  unsigned short* kvTs = smem + 24576;    // [2][64 d][64 r]
  const int tid = threadIdx.x;
  const int lane = tid & 63, wave = tid >> 6;
  const int wr = wave >> 1, wc = wave & 1;
  const int l15 = lane & 15, l4 = lane >> 4;
  const int hp = blockIdx.x, row0 = blockIdx.y * 128;

#pragma unroll
  for (int t = 0; t < 8; t++) {           // q tile: 2048 x 16B
    int c = wave * 512 + t * 64 + lane;
    int r = c >> 4, c8 = c & 15;
    __builtin_amdgcn_global_load_lds(AS1(q + (size_t)(row0 + r) * 1024 + hp * 128 + c8 * 8),
                                     AS3(qs + (wave * 512 + t * 64) * 8), 16, 0, 0);
  }
#pragma unroll
  for (int t = 0; t < 4; t++) {           // kv + kvT: 1024 x 16B each
    int c = wave * 256 + t * 64 + lane;
    int h = c >> 9, r = (c >> 3) & 63, c8 = c & 7;
    __builtin_amdgcn_global_load_lds(AS1(kvb + r * 1024 + (hp * 2 + h) * 64 + c8 * 8),
                                     AS3(kvs + (wave * 256 + t * 64) * 8), 16, 0, 0);
    __builtin_amdgcn_global_load_lds(AS1(kvT + (hp * 2 + h) * 4096 + (c & 511) * 8),
                                     AS3(kvTs + (wave * 256 + t * 64) * 8), 16, 0, 0);
  }
  __syncthreads();

  // scores[row][r] for head wc, rows wr*64..+63
  f32x4 sc[4][4];
#pragma unroll
  for (int i = 0; i < 4; i++)
#pragma unroll
    for (int j = 0; j < 4; j++) sc[i][j] = f32x4{0.f, 0.f, 0.f, 0.f};
#pragma unroll
  for (int ks = 0; ks < 2; ks++) {
    bf16x8 af[4], bfr[4];
#pragma unroll
    for (int i = 0; i < 4; i++)
      af[i] = *(const bf16x8*)(qs + (wr * 64 + i * 16 + l15) * 128 + wc * 64 + ks * 32 + l4 * 8);
#pragma unroll
    for (int j = 0; j < 4; j++)
      bfr[j] = *(const bf16x8*)(kvs + wc * 4096 + (j * 16 + l15) * 64 + ks * 32 + l4 * 8);
#pragma unroll
    for (int i = 0; i < 4; i++)
#pragma unroll
      for (int j = 0; j < 4; j++)
        sc[i][j] = __builtin_amdgcn_mfma_f32_16x16x32_bf16(af[i], bfr[j], sc[i][j], 0, 0, 0);
  }
  __syncthreads();  // all qs reads done; attn aliases qs

  unsigned short* attn = qs;  // [2][128][64], wave-private regions
#pragma unroll
  for (int i = 0; i < 4; i++)
#pragma unroll
    for (int v = 0; v < 4; v++) {
      float m = fmaxf(fmaxf(sc[i][0][v], sc[i][1][v]), fmaxf(sc[i][2][v], sc[i][3][v]));
#pragma unroll
      for (int msk = 1; msk <= 8; msk <<= 1) m = fmaxf(m, __shfl_xor(m, msk));
      float e0 = __expf(sc[i][0][v] - m), e1 = __expf(sc[i][1][v] - m);
      float e2 = __expf(sc[i][2][v] - m), e3 = __expf(sc[i][3][v] - m);
      float s = e0 + e1 + e2 + e3;
#pragma unroll
      for (int msk = 1; msk <= 8; msk <<= 1) s += __shfl_xor(s, msk);
      float inv = 1.0f / s;
      int row = wr * 64 + i * 16 + l4 * 4 + v;
      attn[wc * 8192 + row * 64 + 0 * 16 + l15] = f2bf(e0 * inv);
      attn[wc * 8192 + row * 64 + 1 * 16 + l15] = f2bf(e1 * inv);
      attn[wc * 8192 + row * 64 + 2 * 16 + l15] = f2bf(e2 * inv);
      attn[wc * 8192 + row * 64 + 3 * 16 + l15] = f2bf(e3 * inv);
    }

  // out[row][d] = attn @ kv   (B = kvT[d][r])
  f32x4 o[4][4];
#pragma unroll
  for (int i = 0; i < 4; i++)
#pragma unroll
    for (int j = 0; j < 4; j++) o[i][j] = f32x4{0.f, 0.f, 0.f, 0.f};
#pragma unroll
  for (int ks = 0; ks < 2; ks++) {
    bf16x8 af[4], bfr[4];
#pragma unroll
    for (int i = 0; i < 4; i++)
      af[i] = *(const bf16x8*)(attn + wc * 8192 + (wr * 64 + i * 16 + l15) * 64 + ks * 32 + l4 * 8);
#pragma unroll
    for (int j = 0; j < 4; j++)
      bfr[j] = *(const bf16x8*)(kvTs + wc * 4096 + (j * 16 + l15) * 64 + ks * 32 + l4 * 8);
#pragma unroll
    for (int i = 0; i < 4; i++)
#pragma unroll
      for (int j = 0; j < 4; j++)
        o[i][j] = __builtin_amdgcn_mfma_f32_16x16x32_bf16(af[i], bfr[j], o[i][j], 0, 0, 0);
  }
#pragma unroll
  for (int i = 0; i < 4; i++)
#pragma unroll
    for (int j = 0; j < 4; j++)
#pragma unroll
      for (int v = 0; v < 4; v++) {
        int row = row0 + wr * 64 + i * 16 + l4 * 4 + v;
        int col = (hp * 2 + wc) * 64 + j * 16 + l15;
        outp[(size_t)row * 1024 + col] = f2bf(o[i][j][v]);
      }
}

// ---------- launch ----------
extern "C" void kernel_launch(void* const* d_in, const int* in_sizes, int n_in,
                              void* d_out, int out_size, void* d_ws, size_t ws_size,
                              hipStream_t stream) {
  const float* x  = (const float*)d_in[0];
  const float* wq = (const float*)d_in[1];
  const float* kv = (const float*)d_in[2];
  const float* wo = (const float*)d_in[3];
  const float* w1 = (const float*)d_in[4];
  const float* b1 = (const float*)d_in[5];
  const float* w2 = (const float*)d_in[6];
  const float* b2 = (const float*)d_in[7];
  char* ws = (char*)d_ws;
  const size_t MB = 1024 * 1024;
  unsigned short* wqT = (unsigned short*)(ws + 0 * MB);
  unsigned short* woT = (unsigned short*)(ws + 2 * MB);
  unsigned short* w1T = (unsigned short*)(ws + 4 * MB);
  unsigned short* w2T = (unsigned short*)(ws + 6 * MB);
  unsigned short* kvb = (unsigned short*)(ws + 8 * MB);
  unsigned short* kvT = (unsigned short*)(ws + 8 * MB + 256 * 1024);
  unsigned short* buf1 = (unsigned short*)(ws + 16 * MB);             // q, then y
  unsigned short* buf2 = (unsigned short*)(ws + 16 * MB + 256 * MB);  // attn_out, then h
  float* out = (float*)d_out;

  hipMemsetAsync(d_out, 0, (size_t)out_size * sizeof(float), stream);
  transpose_w<<<dim3(16, 16, 4), 256, 0, stream>>>(wq, wo, w1, w2, wqT, woT, w1T, w2T);
  convert_kv<<<256, 256, 0, stream>>>(kv, kvb, kvT);

  dim3 g(8, 1024);
  // K1: q = (x @ wq) * R^-0.5
  gemm128<0, true ><<<g, 256, 0, stream>>>(x, wqT, buf1, nullptr, nullptr, nullptr, 0.125f);
  // K2: latent attention
  attn_kernel<<<g, 256, 0, stream>>>(buf1, kvb, kvT, buf2);
  // K3: y = attn_out @ wo
  gemm128<0, false><<<g, 256, 0, stream>>>(buf2, woT, buf1, nullptr, nullptr, nullptr, 1.0f);
  // K4: h = gelu(y @ w1 + b1)
  gemm128<1, false><<<g, 256, 0, stream>>>(buf1, w1T, buf2, b1, nullptr, nullptr, 1.0f);
  // K5: out_final = h @ w2 + b2 + y  -> mean-pool into d_out
  gemm128<2, false><<<g, 256, 0, stream>>>(buf2, w2T, nullptr, b2, buf1, out, 1.0f);
}